// Round 3
// baseline (11.792 us; speedup 1.0000x reference)
//
#include <hip/hip_runtime.h>

#define BUF_LEN 201
#define NP      9
#define DT      0.001f
#define CHANGE_EPS 1e-4f

// Per-channel phase-1: everything up to (and including) the gather addresses.
struct Ch {
    float tgt, cur, frac, tau;
    int p0, p1;
};

__device__ __forceinline__ Ch phase1(
    float tgt, float cur, float prv, float lat, int widx,
    const float* __restrict__ s_axis,
    const float* __restrict__ s_tau,
    const float* __restrict__ s_dead)
{
    Ch c;
    c.tgt = tgt; c.cur = cur;

    bool change = fabsf(tgt - prv) > CHANGE_EPS;
    float pst = change ? cur : lat;

    float lo = s_axis[0], hi = s_axis[NP - 1];
    float xq = fminf(fmaxf(tgt, lo), hi);
    float yq = fminf(fmaxf(pst, lo), hi);

    int ix = 0, iy = 0;
#pragma unroll
    for (int j = 1; j <= NP - 2; ++j) {
        if (xq >= s_axis[j]) ix = j;
        if (yq >= s_axis[j]) iy = j;
    }
    float x0 = s_axis[ix],  x1 = s_axis[ix + 1];
    float y0a = s_axis[iy], y1a = s_axis[iy + 1];
    float tx = (xq - x0) / (x1 - x0);
    float ty = (yq - y0a) / (y1a - y0a);

    float w00 = (1.0f - tx) * (1.0f - ty);
    float w10 = tx * (1.0f - ty);
    float w01 = (1.0f - tx) * ty;
    float w11 = tx * ty;

    int b = ix * NP + iy;
    c.tau   = w00 * s_tau[b]      + w10 * s_tau[b + NP]
            + w01 * s_tau[b + 1]  + w11 * s_tau[b + NP + 1];
    float L = w00 * s_dead[b]     + w10 * s_dead[b + NP]
            + w01 * s_dead[b + 1] + w11 * s_dead[b + NP + 1];

    float d = fminf(fmaxf(L / DT, 0.0f), (float)(BUF_LEN - 1));
    int   i0 = (int)floorf(d);
    c.frac = d - (float)i0;

    int p0 = widx - i0;
    p0 %= BUF_LEN; if (p0 < 0) p0 += BUF_LEN;
    int p1 = p0 - 1; if (p1 < 0) p1 += BUF_LEN;
    c.p0 = p0; c.p1 = p1;
    return c;
}

__device__ __forceinline__ float finish(const Ch& c, float v0, float v1, int widx)
{
    float a = (c.p0 == widx) ? c.tgt : v0;
    float b = (c.p1 == widx) ? c.tgt : v1;
    float p_delayed = (1.0f - c.frac) * a + c.frac * b;
    float alpha = 1.0f - expf(-DT / c.tau);
    return c.cur + alpha * (p_delayed - c.cur);
}

__global__ __launch_bounds__(256) void pam_delay_kernel(
    const float* __restrict__ target,
    const float* __restrict__ current,
    const float* __restrict__ prev_target,
    const float* __restrict__ p_start_latch,
    const float* __restrict__ p_axis,
    const float* __restrict__ tau_table,
    const float* __restrict__ dead_table,
    const float* __restrict__ delay_buf,
    const int*   __restrict__ write_idx_p,
    float* __restrict__ out,
    int n)
{
    __shared__ float s_axis[NP];
    __shared__ float s_tau[NP * NP];
    __shared__ float s_dead[NP * NP];

    int t  = blockIdx.x * blockDim.x + threadIdx.x;
    int c0 = 2 * t;
    bool active = (c0 < n);
    bool pair   = (c0 + 1 < n);

    // Issue the per-thread streaming input loads FIRST so their HBM latency
    // overlaps LDS staging + barrier. (n is even in this harness -> float2.)
    float2 tgt2 = make_float2(0.f, 0.f), cur2 = tgt2, prv2 = tgt2, lat2 = tgt2;
    if (pair) {
        tgt2 = *(const float2*)(target        + c0);
        cur2 = *(const float2*)(current       + c0);
        prv2 = *(const float2*)(prev_target   + c0);
        lat2 = *(const float2*)(p_start_latch + c0);
    } else if (active) {
        tgt2.x = target[c0]; cur2.x = current[c0];
        prv2.x = prev_target[c0]; lat2.x = p_start_latch[c0];
    }
    int widx = *write_idx_p;

    {
        int tt = threadIdx.x;
        if (tt < NP) s_axis[tt] = p_axis[tt];
        if (tt < NP * NP) { s_tau[tt] = tau_table[tt]; s_dead[tt] = dead_table[tt]; }
    }
    __syncthreads();

    if (!active) return;

    // Phase 1 for both channels (pure ALU + LDS), then issue all 4 gather
    // taps back-to-back for maximum memory-level parallelism.
    Ch a = phase1(tgt2.x, cur2.x, prv2.x, lat2.x, widx, s_axis, s_tau, s_dead);
    Ch b = a;
    if (pair)
        b = phase1(tgt2.y, cur2.y, prv2.y, lat2.y, widx, s_axis, s_tau, s_dead);

    const float* rowA = delay_buf + (size_t)c0 * BUF_LEN;
    const float* rowB = rowA + BUF_LEN;

    float va0 = rowA[a.p0];
    float va1 = rowA[a.p1];
    float vb0 = 0.f, vb1 = 0.f;
    if (pair) {
        vb0 = rowB[b.p0];
        vb1 = rowB[b.p1];
    }

    float oa = finish(a, va0, va1, widx);
    if (pair) {
        float ob = finish(b, vb0, vb1, widx);
        *(float2*)(out + c0) = make_float2(oa, ob);
    } else {
        out[c0] = oa;
    }
}

extern "C" void kernel_launch(void* const* d_in, const int* in_sizes, int n_in,
                              void* d_out, int out_size, void* d_ws, size_t ws_size,
                              hipStream_t stream) {
    const float* target        = (const float*)d_in[0];
    const float* current       = (const float*)d_in[1];
    const float* prev_target   = (const float*)d_in[2];
    const float* p_start_latch = (const float*)d_in[3];
    const float* p_axis        = (const float*)d_in[4];
    const float* tau_table     = (const float*)d_in[5];
    const float* dead_table    = (const float*)d_in[6];
    const float* delay_buf     = (const float*)d_in[7];
    const int*   write_idx     = (const int*)d_in[8];
    float* out = (float*)d_out;

    int n = in_sizes[0];
    int threads = (n + 1) / 2;
    int block = 256;
    int grid = (threads + block - 1) / block;
    pam_delay_kernel<<<grid, block, 0, stream>>>(
        target, current, prev_target, p_start_latch,
        p_axis, tau_table, dead_table, delay_buf, write_idx, out, n);
}